// Round 3
// baseline (299.683 us; speedup 1.0000x reference)
//
#include <hip/hip_runtime.h>
#include <math.h>

// Sum-product network over a binary tree. B=256, D=1024 leaves, K=128.
// Per level: product (add adjacent children's log-probs) then log-space mixture:
//   out[b,i] = m[b] + log( sum_j exp(w[i,j]) * exp(p[b,j]-m[b]) ) - log( sum_j exp(w[i,j]) )
// GEMM via MFMA 16x16x32 bf16 split-precision (hi+lo, 3 MFMAs), error ~1e-5.
// W planes (exp, split, pre-swizzled) are precomputed once into d_ws, then
// DMA'd to LDS with global_load_lds (linear dest, swizzled source+reads).

#define DD 1024
#define KK 128
#define NT 512
#define HALF_LOG_2PI 0.9189385332046727f

typedef __attribute__((ext_vector_type(8))) short bf16x8;
typedef __attribute__((ext_vector_type(4))) float f32x4;

__device__ __forceinline__ unsigned short bf16_rn(float f) {
    unsigned u = __builtin_bit_cast(unsigned, f);
    u += 0x7fffu + ((u >> 16) & 1u);
    return (unsigned short)(u >> 16);
}
__device__ __forceinline__ float bf16f(unsigned short h) {
    unsigned u = ((unsigned)h) << 16;
    return __builtin_bit_cast(float, u);
}
__device__ __forceinline__ void gload_lds16(const void* g, void* l) {
    __builtin_amdgcn_global_load_lds(
        (const __attribute__((address_space(1))) unsigned int*)g,
        (__attribute__((address_space(3))) unsigned int*)l, 16, 0, 0);
}

// ---------- W precompute: exp, split bf16 hi/lo (pre-swizzled), log row sums --
__global__ __launch_bounds__(256, 4) void w_pre(
    const float* __restrict__ weights, unsigned short* __restrict__ wpl,
    float* __restrict__ lrs)
{
    __shared__ float red[256];
    const int node = blockIdx.x;          // 0..1022
    const int t = threadIdx.x;
    const int i = t >> 1, h = t & 1;      // row, half
    const float* wg = weights + ((size_t)node << 14) + (i << 7) + (h << 6);
    unsigned short* wh = wpl + ((size_t)node << 15) + i * 128;   // hi plane
    unsigned short* wl = wh + 16384;                             // lo plane
    const int sw = (i & 7) << 3;          // swizzle in ushort units
    float ps = 0.f;
    #pragma unroll
    for (int c = 0; c < 8; ++c) {
        float4 v0 = *(const float4*)(wg + 8 * c);
        float4 v1 = *(const float4*)(wg + 8 * c + 4);
        float e[8] = {__expf(v0.x), __expf(v0.y), __expf(v0.z), __expf(v0.w),
                      __expf(v1.x), __expf(v1.y), __expf(v1.z), __expf(v1.w)};
        bf16x8 hv, lv;
        #pragma unroll
        for (int q = 0; q < 8; ++q) {
            ps += e[q];
            const unsigned short hb = bf16_rn(e[q]);
            hv[q] = (short)hb;
            lv[q] = (short)bf16_rn(e[q] - bf16f(hb));
        }
        const int j0 = (h << 6) + 8 * c;
        *(bf16x8*)&wh[j0 ^ sw] = hv;
        *(bf16x8*)&wl[j0 ^ sw] = lv;
    }
    red[t] = ps;
    __syncthreads();
    if (t < 128) lrs[(size_t)node * 128 + t] = __logf(red[2 * t] + red[2 * t + 1]);
}

// ---------------- per-level kernel ------------------------------------------
template <int BT, bool LEAF, bool PRE>
__global__ __launch_bounds__(NT, 2) void spn_level(
    const float* __restrict__ x, const float* __restrict__ mu,
    const float* __restrict__ ls, const float* __restrict__ yprev,
    const float* __restrict__ weights, const unsigned short* __restrict__ wpl,
    const float* __restrict__ lrsg, float* __restrict__ yout,
    int d, int woff)
{
    constexpr int JPT = NT / BT;    // threads per b-row
    constexpr int JW  = KK / JPT;   // j elems per thread

    extern __shared__ char smem[];
    unsigned short* Whi = (unsigned short*)smem;   // [128][128] hi, then lo (64KB)
    unsigned short* Wlo = Whi + 16384;
    unsigned short* Ehi = Wlo + 16384;             // [BT][128]
    unsigned short* Elo = Ehi + BT * 128;
    float* logrs = (float*)(Elo + BT * 128);       // [128]
    float* mrow  = logrs + 128;                    // [BT]
    float* redE  = mrow + BT;                      // [NT]
    float* redW  = redE + NT;                      // [NT] (inline-W fallback only)
    float* musig = redW + NT;                      // [768] leaf constants

    const int n     = blockIdx.x;
    const int btile = blockIdx.y;
    const int t     = threadIdx.x;
    const int node  = woff + n;

    // ---------------- Phase 1: W into LDS (DMA or inline) + leaf constants ----
    if (PRE) {
        const int wv = t >> 6, ln = t & 63;
        const char* gsrc = (const char*)(wpl + ((size_t)node << 15)) + wv * 8192 + (size_t)ln * 16;
        char* ldst = (char*)Whi + wv * 8192;       // wave-uniform dest
        #pragma unroll
        for (int q = 0; q < 8; ++q)
            gload_lds16(gsrc + q * 1024, ldst + q * 1024);
        if (t < 128) logrs[t] = lrsg[(size_t)node * 128 + t];
    } else {
        const int i = t >> 2, h = t & 3;           // 4 threads per W row
        const float* wg = weights + ((size_t)node << 14) + (i << 7) + (h << 5);
        unsigned short* wh = Whi + i * 128;
        unsigned short* wl = Wlo + i * 128;
        const int sw = (i & 7) << 3;
        float ps = 0.f;
        #pragma unroll
        for (int c = 0; c < 4; ++c) {
            float4 v0 = *(const float4*)(wg + 8 * c);
            float4 v1 = *(const float4*)(wg + 8 * c + 4);
            float e[8] = {__expf(v0.x), __expf(v0.y), __expf(v0.z), __expf(v0.w),
                          __expf(v1.x), __expf(v1.y), __expf(v1.z), __expf(v1.w)};
            bf16x8 hv, lv;
            #pragma unroll
            for (int q = 0; q < 8; ++q) {
                ps += e[q];
                const unsigned short hb = bf16_rn(e[q]);
                hv[q] = (short)hb;
                lv[q] = (short)bf16_rn(e[q] - bf16f(hb));
            }
            const int j0 = (h << 5) + 8 * c;
            *(bf16x8*)&wh[j0 ^ sw] = hv;
            *(bf16x8*)&wl[j0 ^ sw] = lv;
        }
        redW[t] = ps;
    }
    if (LEAF && t < 256) {
        const int c = t >> 7, j = t & 127;
        const float lsv = ls[(size_t)(2 * n + c) * KK + j];
        musig[c * 128 + j]       = __expf(-lsv);
        musig[256 + c * 128 + j] = -lsv - HALF_LOG_2PI;
        musig[512 + c * 128 + j] = mu[(size_t)(2 * n + c) * KK + j];
    }
    __syncthreads();   // bar0 (drains W DMA too)

    // ---------------- Phase 2: logrs (fallback) + E products ------------------
    if (!PRE && t < 128)
        logrs[t] = __logf(redW[4 * t] + redW[4 * t + 1] + redW[4 * t + 2] + redW[4 * t + 3]);

    const int bl = t & (BT - 1);
    const int jh = t / BT;
    const int b  = btile * BT + bl;
    float p[JW];
    float lmax = -3.0e38f;
    if (LEAF) {
        const float xa = x[(size_t)b * DD + 2 * n];
        const float xb = x[(size_t)b * DD + 2 * n + 1];
        const float* isga = musig;        const float* isgb = musig + 128;
        const float* cta  = musig + 256;  const float* ctb  = musig + 384;
        const float* mva  = musig + 512;  const float* mvb  = musig + 640;
        #pragma unroll
        for (int c = 0; c < JW / 4; ++c) {
            const int j = jh * JW + 4 * c;
            const float4 ia = *(const float4*)(isga + j);
            const float4 ib = *(const float4*)(isgb + j);
            const float4 ca = *(const float4*)(cta + j);
            const float4 cb = *(const float4*)(ctb + j);
            const float4 ma = *(const float4*)(mva + j);
            const float4 mb = *(const float4*)(mvb + j);
            float za, zb, v;
            za = (xa - ma.x) * ia.x; zb = (xb - mb.x) * ib.x;
            v = fmaf(-0.5f * za, za, ca.x) + fmaf(-0.5f * zb, zb, cb.x);
            p[4 * c + 0] = v; lmax = fmaxf(lmax, v);
            za = (xa - ma.y) * ia.y; zb = (xb - mb.y) * ib.y;
            v = fmaf(-0.5f * za, za, ca.y) + fmaf(-0.5f * zb, zb, cb.y);
            p[4 * c + 1] = v; lmax = fmaxf(lmax, v);
            za = (xa - ma.z) * ia.z; zb = (xb - mb.z) * ib.z;
            v = fmaf(-0.5f * za, za, ca.z) + fmaf(-0.5f * zb, zb, cb.z);
            p[4 * c + 2] = v; lmax = fmaxf(lmax, v);
            za = (xa - ma.w) * ia.w; zb = (xb - mb.w) * ib.w;
            v = fmaf(-0.5f * za, za, ca.w) + fmaf(-0.5f * zb, zb, cb.w);
            p[4 * c + 3] = v; lmax = fmaxf(lmax, v);
        }
    } else {
        const float* ra = yprev + ((size_t)b * (2 * d) + 2 * n) * KK + jh * JW;
        const float* rb = ra + KK;
        #pragma unroll
        for (int c = 0; c < JW / 4; ++c) {
            const float4 a4 = *(const float4*)(ra + 4 * c);
            const float4 b4 = *(const float4*)(rb + 4 * c);
            const float p0 = a4.x + b4.x, p1 = a4.y + b4.y;
            const float p2 = a4.z + b4.z, p3 = a4.w + b4.w;
            p[4 * c + 0] = p0; p[4 * c + 1] = p1;
            p[4 * c + 2] = p2; p[4 * c + 3] = p3;
            lmax = fmaxf(lmax, fmaxf(fmaxf(p0, p1), fmaxf(p2, p3)));
        }
    }
    redE[t] = lmax;
    __syncthreads();   // bar1

    // ---------------- Phase 3: row max + exp/split/store E --------------------
    if (t < BT) {
        float m = redE[t];
        #pragma unroll
        for (int q = 1; q < JPT; ++q) m = fmaxf(m, redE[t + BT * q]);
        mrow[t] = m;
    }
    float mx = redE[bl];
    #pragma unroll
    for (int q = 1; q < JPT; ++q) mx = fmaxf(mx, redE[bl + BT * q]);
    {
        const int sw = (bl & 7) << 3;
        unsigned short* eh = Ehi + bl * 128;
        unsigned short* el = Elo + bl * 128;
        #pragma unroll
        for (int c = 0; c < JW / 8; ++c) {
            bf16x8 hv, lv;
            #pragma unroll
            for (int q = 0; q < 8; ++q) {
                const float ev = __expf(p[8 * c + q] - mx);
                const unsigned short hb = bf16_rn(ev);
                hv[q] = (short)hb;
                lv[q] = (short)bf16_rn(ev - bf16f(hb));
            }
            const int j0 = jh * JW + 8 * c;
            *(bf16x8*)&eh[j0 ^ sw] = hv;
            *(bf16x8*)&el[j0 ^ sw] = lv;
        }
    }
    __syncthreads();   // bar2: E planes, mrow, logrs ready

    // ---------------- Phase 4: MFMA GEMM + log epilogue -----------------------
    // s[b,i] = sum_j E[b,j] * Wexp[i,j]  (both frags row-contiguous, B^T style)
    const int wv = t >> 6;
    const int ln = t & 63;
    const int lr = ln & 15;
    const int lk = ln >> 4;
    constexpr int NWB = (BT == 128) ? 2 : 1;   // row tiles per wave
    constexpr int NCI = (BT == 128) ? 4 : 2;   // col tiles per wave
    const int wr = (BT == 128) ? (wv >> 1) : (wv & 1);
    const int wc = (BT == 128) ? (wv & 1) : (wv >> 1);
    const int bt0 = wr * NWB;
    const int it0 = wc * NCI;

    f32x4 acc[NWB][NCI];
    #pragma unroll
    for (int bi = 0; bi < NWB; ++bi)
        #pragma unroll
        for (int ci = 0; ci < NCI; ++ci) acc[bi][ci] = (f32x4){0.f, 0.f, 0.f, 0.f};

    const int kb = lk * 8;
    #pragma unroll
    for (int ks = 0; ks < 4; ++ks) {
        const int jo = ks * 32 + kb;
        bf16x8 ah[NWB], al[NWB];
        #pragma unroll
        for (int bi = 0; bi < NWB; ++bi) {
            const int r = (bt0 + bi) * 16 + lr;
            const int idx = r * 128 + (jo ^ ((r & 7) << 3));
            ah[bi] = *(bf16x8*)&Ehi[idx];
            al[bi] = *(bf16x8*)&Elo[idx];
        }
        #pragma unroll
        for (int ci = 0; ci < NCI; ++ci) {
            const int r = (it0 + ci) * 16 + lr;
            const int idx = r * 128 + (jo ^ ((r & 7) << 3));
            const bf16x8 bh  = *(bf16x8*)&Whi[idx];
            const bf16x8 blo = *(bf16x8*)&Wlo[idx];
            #pragma unroll
            for (int bi = 0; bi < NWB; ++bi) {
                acc[bi][ci] = __builtin_amdgcn_mfma_f32_16x16x32_bf16(ah[bi], bh,  acc[bi][ci], 0, 0, 0);
                acc[bi][ci] = __builtin_amdgcn_mfma_f32_16x16x32_bf16(ah[bi], blo, acc[bi][ci], 0, 0, 0);
                acc[bi][ci] = __builtin_amdgcn_mfma_f32_16x16x32_bf16(al[bi], bh,  acc[bi][ci], 0, 0, 0);
            }
        }
    }

    #pragma unroll
    for (int bi = 0; bi < NWB; ++bi) {
        const int brl = (bt0 + bi) * 16 + lk * 4;   // C/D: row=(ln>>4)*4+reg
        #pragma unroll
        for (int ci = 0; ci < NCI; ++ci) {
            const int ic = (it0 + ci) * 16 + lr;    // C/D: col=lane&15
            const float lrsv = logrs[ic];
            const f32x4 a = acc[bi][ci];
            #pragma unroll
            for (int r = 0; r < 4; ++r) {
                const float m = mrow[brl + r];
                const size_t off = ((size_t)(btile * BT + brl + r) * d + n) * KK + ic;
                yout[off] = m + __logf(a[r]) - lrsv;
            }
        }
    }
}

extern "C" void kernel_launch(void* const* d_in, const int* in_sizes, int n_in,
                              void* d_out, int out_size, void* d_ws, size_t ws_size,
                              hipStream_t stream) {
    const float* x  = (const float*)d_in[0];
    const float* mu = (const float*)d_in[1];
    const float* ls = (const float*)d_in[2];
    const float* w  = (const float*)d_in[3];
    float* out  = (float*)d_out;
    float* buf0 = (float*)d_ws;                       // [256][512][128] f32 = 67.1MB
    float* buf1 = buf0 + (size_t)256 * 512 * KK;      // [256][256][128] f32 = 33.6MB
    unsigned short* wpl = (unsigned short*)(buf1 + (size_t)256 * 256 * KK);  // 67.0MB
    float* lrs = (float*)(wpl + (size_t)1023 * 32768);                       // 0.52MB

    const size_t NEED = ((size_t)(256 * 512 * 128) + (size_t)(256 * 256 * 128)) * 4
                      + (size_t)1023 * 32768 * 2 + (size_t)1023 * 128 * 4;
    const bool pre = ws_size >= NEED;

    const int shA = 65536 + 65536 + 512 + 512 + NT * 4 + NT * 4 + 3072;  // BT=128: 139264
    const int shB = 65536 + 16384 + 512 + 128 + NT * 4 + NT * 4;         // BT=32:   86656

    (void)hipFuncSetAttribute((const void*)spn_level<128, true,  true >, hipFuncAttributeMaxDynamicSharedMemorySize, shA);
    (void)hipFuncSetAttribute((const void*)spn_level<128, true,  false>, hipFuncAttributeMaxDynamicSharedMemorySize, shA);
    (void)hipFuncSetAttribute((const void*)spn_level<128, false, true >, hipFuncAttributeMaxDynamicSharedMemorySize, shA);
    (void)hipFuncSetAttribute((const void*)spn_level<128, false, false>, hipFuncAttributeMaxDynamicSharedMemorySize, shA);
    (void)hipFuncSetAttribute((const void*)spn_level<32,  false, true >, hipFuncAttributeMaxDynamicSharedMemorySize, shB);
    (void)hipFuncSetAttribute((const void*)spn_level<32,  false, false>, hipFuncAttributeMaxDynamicSharedMemorySize, shB);

    if (pre) w_pre<<<dim3(1023), dim3(256), 0, stream>>>(w, wpl, lrs);

    // Level 1 (d=512): leaves fused, weights[0:512], out -> buf0
    if (pre)
        spn_level<128, true, true><<<dim3(512, 2), dim3(NT), shA, stream>>>(
            x, mu, ls, nullptr, w, wpl, lrs, buf0, 512, 0);
    else
        spn_level<128, true, false><<<dim3(512, 2), dim3(NT), shA, stream>>>(
            x, mu, ls, nullptr, w, wpl, lrs, buf0, 512, 0);

    const float* src = buf0;
    float* other = buf1;
    int woff = 512;
    for (int d = 256; d >= 1; d >>= 1) {
        float* o = (d == 1) ? out : other;
        if (d >= 64) {
            if (pre)
                spn_level<128, false, true><<<dim3(d, 2), dim3(NT), shA, stream>>>(
                    nullptr, nullptr, nullptr, src, w, wpl, lrs, o, d, woff);
            else
                spn_level<128, false, false><<<dim3(d, 2), dim3(NT), shA, stream>>>(
                    nullptr, nullptr, nullptr, src, w, wpl, lrs, o, d, woff);
        } else {
            if (pre)
                spn_level<32, false, true><<<dim3(d, 8), dim3(NT), shB, stream>>>(
                    nullptr, nullptr, nullptr, src, w, wpl, lrs, o, d, woff);
            else
                spn_level<32, false, false><<<dim3(d, 8), dim3(NT), shB, stream>>>(
                    nullptr, nullptr, nullptr, src, w, wpl, lrs, o, d, woff);
        }
        woff += d;
        other = (float*)src;
        src = o;
    }
}

// Round 4
// 245.258 us; speedup vs baseline: 1.2219x; 1.2219x over previous
//
#include <hip/hip_runtime.h>
#include <math.h>

// Sum-product network over a binary tree. B=256, D=1024 leaves, K=128.
// Per level: product (add adjacent children's log-probs) then log-space mixture:
//   out[b,i] = m[b] + log( sum_j exp(w[i,j]) * exp(p[b,j]-m[b]) ) - log( sum_j exp(w[i,j]) )
// GEMM via MFMA 16x16x32 bf16 split-precision (hi+lo, 3 MFMAs), error < fp32 ulp
// of the output. E (exp of shifted products) lives entirely in registers as MFMA
// A-fragments; only W planes go through LDS -> ~69KB/block -> 2 blocks/CU,
// 4 waves/SIMD (vs 1 in earlier rounds).

#define DD 1024
#define KK 128
#define HALF_LOG_2PI 0.9189385332046727f

typedef __attribute__((ext_vector_type(8))) short bf16x8;
typedef __attribute__((ext_vector_type(4))) float f32x4;

__device__ __forceinline__ unsigned short bf16_rn(float f) {
    unsigned u = __builtin_bit_cast(unsigned, f);
    u += 0x7fffu + ((u >> 16) & 1u);
    return (unsigned short)(u >> 16);
}
__device__ __forceinline__ float bf16f(unsigned short h) {
    unsigned u = ((unsigned)h) << 16;
    return __builtin_bit_cast(float, u);
}

// BT: batch rows per block. NTH: threads. Wave w handles row-tile w/WPR,
// col-tiles (w%WPR)*NCI .. +NCI-1. Lane ln: A-row = tile*16 + (ln&15),
// k-chunk = (ln>>4)*8 + ks*32  (validated layout, R2/R3 absmax=0).
template <int BT, int NTH, bool LEAF>
__global__ __launch_bounds__(NTH, 4) void spn_level(
    const float* __restrict__ x, const float* __restrict__ mu,
    const float* __restrict__ ls, const float* __restrict__ yprev,
    const float* __restrict__ weights, float* __restrict__ yout,
    int d, int woff)
{
    constexpr int NW  = NTH / 64;   // waves per block
    constexpr int NRT = BT / 16;    // row-tiles per block
    constexpr int WPR = NW / NRT;   // waves sharing a row-tile (split cols)
    constexpr int NCI = 8 / WPR;    // col-tiles per wave

    extern __shared__ char smem[];
    unsigned short* Whi = (unsigned short*)smem;     // [128][128] bf16 hi
    unsigned short* Wlo = Whi + 16384;               // [128][128] bf16 lo
    float* logrs = (float*)(Wlo + 16384);            // [128]
    float* musig = logrs + 128;                      // [768] leaf constants

    const int n     = blockIdx.x;
    const int btile = blockIdx.y;
    const int t     = threadIdx.x;
    const int node  = woff + n;

    // ---------------- Phase 1: W stage (exp, split, swizzled) + log rowsums ----
    {
        constexpr int TPR = NTH / 128;   // threads per W row
        constexpr int EPT = 128 / TPR;   // elems per thread
        const int i = t / TPR, h = t % TPR;
        const float* wr = weights + ((size_t)node << 14) + i * 128 + h * EPT;
        unsigned short* wh = Whi + i * 128;
        unsigned short* wl = Wlo + i * 128;
        const int sw = (i & 7) << 3;     // XOR swizzle (ushort units)
        float ps = 0.f;
        #pragma unroll
        for (int c = 0; c < EPT / 8; ++c) {
            float4 v0 = *(const float4*)(wr + 8 * c);
            float4 v1 = *(const float4*)(wr + 8 * c + 4);
            float e[8] = {__expf(v0.x), __expf(v0.y), __expf(v0.z), __expf(v0.w),
                          __expf(v1.x), __expf(v1.y), __expf(v1.z), __expf(v1.w)};
            bf16x8 hv, lv;
            #pragma unroll
            for (int q = 0; q < 8; ++q) {
                ps += e[q];
                const unsigned short hb = bf16_rn(e[q]);
                hv[q] = (short)hb;
                lv[q] = (short)bf16_rn(e[q] - bf16f(hb));
            }
            const int j0 = h * EPT + 8 * c;
            *(bf16x8*)&wh[j0 ^ sw] = hv;
            *(bf16x8*)&wl[j0 ^ sw] = lv;
        }
        // in-wave rowsum (TPR adjacent lanes share a row) -> no extra barrier
        #pragma unroll
        for (int s2 = 1; s2 < TPR; s2 <<= 1) ps += __shfl_xor(ps, s2);
        if (h == 0) logrs[i] = __logf(ps);
    }
    if (LEAF && t < 256) {
        const int c = t >> 7, j = t & 127;
        const float lsv = ls[(size_t)(2 * n + c) * KK + j];
        musig[c * 128 + j]       = __expf(-lsv);
        musig[256 + c * 128 + j] = -lsv - HALF_LOG_2PI;
        musig[512 + c * 128 + j] = mu[(size_t)(2 * n + c) * KK + j];
    }
    __syncthreads();   // W planes, logrs, musig ready

    // ---------------- Phase 2: E fragments in registers ------------------------
    const int w  = t >> 6;
    const int ln = t & 63;
    const int lr = ln & 15;
    const int lk = ln >> 4;
    const int rt  = w / WPR;
    const int ci0 = (w % WPR) * NCI;
    const int brow = btile * BT + rt * 16 + lr;   // this lane's A-row (global b)

    float p[32];
    if (LEAF) {
        const float xa = x[(size_t)brow * DD + 2 * n];
        const float xb = x[(size_t)brow * DD + 2 * n + 1];
        #pragma unroll
        for (int ks = 0; ks < 4; ++ks) {
            #pragma unroll
            for (int g = 0; g < 2; ++g) {
                const int j = ks * 32 + lk * 8 + 4 * g;
                const float4 ia = *(const float4*)&musig[j];
                const float4 ib = *(const float4*)&musig[128 + j];
                const float4 ca = *(const float4*)&musig[256 + j];
                const float4 cb = *(const float4*)&musig[384 + j];
                const float4 ma = *(const float4*)&musig[512 + j];
                const float4 mb = *(const float4*)&musig[640 + j];
                float za, zb;
                za = (xa - ma.x) * ia.x; zb = (xb - mb.x) * ib.x;
                p[ks * 8 + 4 * g + 0] = fmaf(-0.5f * za, za, ca.x) + fmaf(-0.5f * zb, zb, cb.x);
                za = (xa - ma.y) * ia.y; zb = (xb - mb.y) * ib.y;
                p[ks * 8 + 4 * g + 1] = fmaf(-0.5f * za, za, ca.y) + fmaf(-0.5f * zb, zb, cb.y);
                za = (xa - ma.z) * ia.z; zb = (xb - mb.z) * ib.z;
                p[ks * 8 + 4 * g + 2] = fmaf(-0.5f * za, za, ca.z) + fmaf(-0.5f * zb, zb, cb.z);
                za = (xa - ma.w) * ia.w; zb = (xb - mb.w) * ib.w;
                p[ks * 8 + 4 * g + 3] = fmaf(-0.5f * za, za, ca.w) + fmaf(-0.5f * zb, zb, cb.w);
            }
        }
    } else {
        const float* ra = yprev + ((size_t)brow * (2 * d) + 2 * n) * KK;
        #pragma unroll
        for (int ks = 0; ks < 4; ++ks) {
            const int j0 = ks * 32 + lk * 8;
            const float4 a0 = *(const float4*)(ra + j0);
            const float4 a1 = *(const float4*)(ra + j0 + 4);
            const float4 b0 = *(const float4*)(ra + KK + j0);
            const float4 b1 = *(const float4*)(ra + KK + j0 + 4);
            p[ks * 8 + 0] = a0.x + b0.x; p[ks * 8 + 1] = a0.y + b0.y;
            p[ks * 8 + 2] = a0.z + b0.z; p[ks * 8 + 3] = a0.w + b0.w;
            p[ks * 8 + 4] = a1.x + b1.x; p[ks * 8 + 5] = a1.y + b1.y;
            p[ks * 8 + 6] = a1.z + b1.z; p[ks * 8 + 7] = a1.w + b1.w;
        }
    }

    // row max: local tree over 32 elems, then across the 4 lanes sharing a row
    float m16[16];
    #pragma unroll
    for (int q = 0; q < 16; ++q) m16[q] = fmaxf(p[q], p[q + 16]);
    float m8[8];
    #pragma unroll
    for (int q = 0; q < 8; ++q) m8[q] = fmaxf(m16[q], m16[q + 8]);
    float m4a[4];
    #pragma unroll
    for (int q = 0; q < 4; ++q) m4a[q] = fmaxf(m8[q], m8[q + 4]);
    float mx = fmaxf(fmaxf(m4a[0], m4a[1]), fmaxf(m4a[2], m4a[3]));
    mx = fmaxf(mx, __shfl_xor(mx, 16));
    mx = fmaxf(mx, __shfl_xor(mx, 32));

    // exp + split into A fragments (hi/lo)
    bf16x8 ah[4], al[4];
    #pragma unroll
    for (int ks = 0; ks < 4; ++ks) {
        #pragma unroll
        for (int q = 0; q < 8; ++q) {
            const float ev = __expf(p[ks * 8 + q] - mx);
            const unsigned short hb = bf16_rn(ev);
            ah[ks][q] = (short)hb;
            al[ks][q] = (short)bf16_rn(ev - bf16f(hb));
        }
    }

    // ---------------- Phase 3: MFMA GEMM ---------------------------------------
    f32x4 acc[NCI];
    #pragma unroll
    for (int ci = 0; ci < NCI; ++ci) acc[ci] = (f32x4){0.f, 0.f, 0.f, 0.f};
    #pragma unroll
    for (int ci = 0; ci < NCI; ++ci) {
        const int i = (ci0 + ci) * 16 + lr;
        const int base = i * 128;
        const int sw = (i & 7) << 3;
        #pragma unroll
        for (int ks = 0; ks < 4; ++ks) {
            const int idx = base + ((ks * 32 + lk * 8) ^ sw);
            const bf16x8 bh = *(bf16x8*)&Whi[idx];
            const bf16x8 bl = *(bf16x8*)&Wlo[idx];
            acc[ci] = __builtin_amdgcn_mfma_f32_16x16x32_bf16(ah[ks], bh, acc[ci], 0, 0, 0);
            acc[ci] = __builtin_amdgcn_mfma_f32_16x16x32_bf16(ah[ks], bl, acc[ci], 0, 0, 0);
            acc[ci] = __builtin_amdgcn_mfma_f32_16x16x32_bf16(al[ks], bh, acc[ci], 0, 0, 0);
        }
    }

    // ---------------- Phase 4: log epilogue + store ----------------------------
    // C/D layout: col = ln&15, row = (ln>>4)*4 + reg
    float mv4[4];
    #pragma unroll
    for (int r = 0; r < 4; ++r) mv4[r] = __shfl(mx, lk * 4 + r);
    #pragma unroll
    for (int ci = 0; ci < NCI; ++ci) {
        const int icol = (ci0 + ci) * 16 + lr;
        const float lrsv = logrs[icol];
        #pragma unroll
        for (int r = 0; r < 4; ++r) {
            const int b = btile * BT + rt * 16 + lk * 4 + r;
            yout[((size_t)b * d + n) * KK + icol] = mv4[r] + __logf(acc[ci][r]) - lrsv;
        }
    }
}

extern "C" void kernel_launch(void* const* d_in, const int* in_sizes, int n_in,
                              void* d_out, int out_size, void* d_ws, size_t ws_size,
                              hipStream_t stream) {
    const float* x  = (const float*)d_in[0];
    const float* mu = (const float*)d_in[1];
    const float* ls = (const float*)d_in[2];
    const float* w  = (const float*)d_in[3];
    float* out  = (float*)d_out;
    float* buf0 = (float*)d_ws;                       // [256][512][128] f32 = 67.1MB
    float* buf1 = buf0 + (size_t)256 * 512 * KK;      // [256][256][128] f32 = 33.6MB

    const int shBig   = 65536 + 512 + 3072;  // W planes + logrs + musig = 69120
    const int shSmall = 65536 + 512;         // 66048

    (void)hipFuncSetAttribute((const void*)spn_level<128, 512, true>,
                              hipFuncAttributeMaxDynamicSharedMemorySize, shBig);
    (void)hipFuncSetAttribute((const void*)spn_level<128, 512, false>,
                              hipFuncAttributeMaxDynamicSharedMemorySize, shBig);
    (void)hipFuncSetAttribute((const void*)spn_level<32, 256, false>,
                              hipFuncAttributeMaxDynamicSharedMemorySize, shSmall);

    // Level 1 (d=512): leaves fused, weights[0:512], out -> buf0
    spn_level<128, 512, true><<<dim3(512, 2), dim3(512), shBig, stream>>>(
        x, mu, ls, nullptr, w, buf0, 512, 0);

    const float* src = buf0;
    float* other = buf1;
    int woff = 512;
    for (int d = 256; d >= 1; d >>= 1) {
        float* o = (d == 1) ? out : other;
        if (d >= 64) {
            spn_level<128, 512, false><<<dim3(d, 2), dim3(512), shBig, stream>>>(
                nullptr, nullptr, nullptr, src, w, o, d, woff);
        } else {
            spn_level<32, 256, false><<<dim3(d, 8), dim3(256), shSmall, stream>>>(
                nullptr, nullptr, nullptr, src, w, o, d, woff);
        }
        woff += d;
        other = (float*)src;
        src = o;
    }
}